// Round 13
// baseline (61.408 us; speedup 1.0000x reference)
//
#include <hip/hip_runtime.h>
#include <hip/hip_bf16.h>
#include <stdint.h>

#define B_ 4
#define K_ 2048
#define D_ 512
#define H_ 8
#define ATTN_ 128
#define M_ (B_ * K_)   // 8192

typedef __attribute__((ext_vector_type(4))) float f32x4;
typedef __attribute__((ext_vector_type(8))) short bf16x8;
typedef __attribute__((ext_vector_type(8))) unsigned short u16x8;
typedef __attribute__((ext_vector_type(2))) unsigned int u32x2;

__device__ __forceinline__ unsigned short f2bf(float f) {
    union { float f; unsigned int i; } x; x.f = f;
    unsigned int r = x.i + 0x7fffu + ((x.i >> 16) & 1u);   // RNE
    return (unsigned short)(r >> 16);
}
__device__ __forceinline__ float bf2f(unsigned short u) {
    union { unsigned int i; float f; } x; x.i = ((unsigned int)u) << 16; return x.f;
}
__device__ __forceinline__ void gload_lds16(const unsigned short* g, unsigned short* l) {
    __builtin_amdgcn_global_load_lds(
        (const __attribute__((address_space(1))) void*)g,
        (__attribute__((address_space(3))) void*)l, 16, 0, 0);
}
__device__ __forceinline__ unsigned lds_addr(const void* p) {
    return (unsigned)(unsigned long long)
        (const __attribute__((address_space(3))) void*)p;
}

// ---------------------------------------------------------------------------
// fp32 -> bf16 conversion: weights only (4 tensors)
// ---------------------------------------------------------------------------
struct Cvt { const float* s; unsigned short* d; int n8; };
struct CvtA { Cvt c[4]; };

__global__ __launch_bounds__(256)
void cvt_multi(CvtA a) {
    const Cvt c = a.c[blockIdx.y];
    const float4* s4 = (const float4*)c.s;
    u16x8* d8 = (u16x8*)c.d;
    for (int g = blockIdx.x * 256 + threadIdx.x; g < c.n8; g += gridDim.x * 256) {
        float4 f0 = s4[2 * g], f1 = s4[2 * g + 1];
        u16x8 o;
        o[0] = f2bf(f0.x); o[1] = f2bf(f0.y); o[2] = f2bf(f0.z); o[3] = f2bf(f0.w);
        o[4] = f2bf(f1.x); o[5] = f2bf(f1.y); o[6] = f2bf(f1.z); o[7] = f2bf(f1.w);
        d8[g] = o;
    }
}

// ---------------------------------------------------------------------------
// BK=128 GEMM: C[8192,512] = A @ W^T + bias.  4 K-steps (was 8).
// Model from r4-r12: wall time ~ (K-steps) x ~3.4k cyc, independent of
// per-step work (r7: 16 steps=55us; r4/r8/r12: 8 steps=39-43us). So halve
// the steps: BK=128, 128x128 tile, SINGLE-buffered 64 KB LDS, 256 thr
// (4 waves 2x2, 64x64/wave, 4x4 frags/kk, 4 kk/step = 64 MFMA/wave/step).
// 2 blocks/CU (launch_bounds(256,2)); r12 measured ~2 blocks resident anyway.
// Swizzle (16 chunks/row, stride 128 shorts): stored slot = ch ^ (row&7)
// (low-3-bit XOR, bijective; lanes 0-7 -> 8 disjoint 4-bank windows =
// conflict-free; lanes 8-15 2-way alias = free). Same beat structure as the
// r2-validated BK=64 layout (0 conflicts measured r4/r12).
// A_FP32 (QKV): A fp32->reg at top of step (compute-phase latency cover),
// cvt RNE + ds_write after the read-drain barrier. Else: gload_lds direct.
// ---------------------------------------------------------------------------
struct GArgs {
    const void* A[3];
    const unsigned short* Wt[3];
    const float* bias[3];
    void* C[3];
};

template<bool A_FP32>
__global__ __launch_bounds__(256, 2)
void gemm128k(GArgs args)
{
    __shared__ unsigned short As[128 * 128];     // 32 KB
    __shared__ unsigned short Bs[128 * 128];     // 32 KB

    const int id = blockIdx.x;
    const int lg = (id & 7) * (gridDim.x >> 3) + (id >> 3);  // XCD-contiguous
    const int g  = lg >> 2;                      // m-group (shares A-tile)
    const int nt = lg & 3;
    const int z  = A_FP32 ? (g >> 6) : 0;
    const int mt = A_FP32 ? (g & 63) : g;
    const int bm = mt * 128;
    const int bn = nt * 128;

    const void* Az = args.A[z];
    const unsigned short* Wz = args.Wt[z];
    const float* biz = args.bias[z];
    void* Cz = args.C[z];

    const int tid = threadIdx.x;
    const int w   = tid >> 6;                    // wave 0..3
    const int l   = tid & 63;
    const int lr  = l & 15;
    const int lhi = l >> 4;
    const int wm  = (w >> 1) * 64;               // 2x2 wave grid
    const int wn  = (w & 1) * 64;

    f32x4 acc[4][4];
    #pragma unroll
    for (int m = 0; m < 4; ++m)
        #pragma unroll
        for (int n = 0; n < 4; ++n) acc[m][n] = (f32x4){0.f, 0.f, 0.f, 0.f};

    float4 fa[8][2];   // in-flight fp32 A tile: 16 float4 (64 VGPR)

    // A tile = 128 rows x 16 chunks (8 bf16 each) = 2048 chunks, 8/thread.
    auto loadA_f32 = [&](int t) {
        #pragma unroll
        for (int q = 0; q < 8; ++q) {
            const int cid = q * 256 + tid;
            const int r = cid >> 4;
            const int c = (cid & 15) ^ (r & 7);  // load-side XOR (low 3 bits)
            const float* src = (const float*)Az + (size_t)(bm + r) * D_ + t * 128 + c * 8;
            fa[q][0] = *(const float4*)src;
            fa[q][1] = *(const float4*)(src + 4);
        }
    };
    auto writeA_f32 = [&]() {
        #pragma unroll
        for (int q = 0; q < 8; ++q) {
            const int cid = q * 256 + tid;
            u16x8 o;
            o[0] = f2bf(fa[q][0].x); o[1] = f2bf(fa[q][0].y);
            o[2] = f2bf(fa[q][0].z); o[3] = f2bf(fa[q][0].w);
            o[4] = f2bf(fa[q][1].x); o[5] = f2bf(fa[q][1].y);
            o[6] = f2bf(fa[q][1].z); o[7] = f2bf(fa[q][1].w);
            *(u16x8*)&As[cid * 8] = o;           // linear dest: conflict-free
        }
    };
    auto stageA_b16 = [&](int t) {               // 8 gload_lds groups / wave
        #pragma unroll
        for (int it = 0; it < 8; ++it) {
            const int cg  = it * 4 + w;          // 32 groups of 64 chunks
            const int cid = cg * 64 + l;
            const int r = cid >> 4;
            const int c = (cid & 15) ^ (r & 7);
            gload_lds16((const unsigned short*)Az + (size_t)(bm + r) * D_ + t * 128 + c * 8,
                        &As[cg * 512]);
        }
    };
    auto stageB = [&](int t) {
        #pragma unroll
        for (int it = 0; it < 8; ++it) {
            const int cg  = it * 4 + w;
            const int cid = cg * 64 + l;
            const int r = cid >> 4;
            const int c = (cid & 15) ^ (r & 7);
            gload_lds16(Wz + (size_t)(bn + r) * D_ + t * 128 + c * 8,
                        &Bs[cg * 512]);
        }
    };

    // Prologue: tile 0 staged, drained.
    if (A_FP32) { loadA_f32(0); writeA_f32(); }
    else        { stageA_b16(0); }
    stageB(0);
    __syncthreads();

    for (int t = 0; t < 4; ++t) {                // K = 512 = 4 x 128
        if (A_FP32 && t < 3) loadA_f32(t + 1);   // issue early: compute cover

        __builtin_amdgcn_s_setprio(1);
        #pragma unroll
        for (int kk = 0; kk < 4; ++kk) {
            bf16x8 af[4], bfr[4];
            #pragma unroll
            for (int fm = 0; fm < 4; ++fm) {
                const int row = wm + fm * 16 + lr;
                const int sl  = (kk * 4 + lhi) ^ (row & 7);
                af[fm] = *(const bf16x8*)&As[row * 128 + sl * 8];
            }
            #pragma unroll
            for (int fn = 0; fn < 4; ++fn) {
                const int row = wn + fn * 16 + lr;
                const int sl  = (kk * 4 + lhi) ^ (row & 7);
                bfr[fn] = *(const bf16x8*)&Bs[row * 128 + sl * 8];
            }
            #pragma unroll
            for (int fm = 0; fm < 4; ++fm)
                #pragma unroll
                for (int fn = 0; fn < 4; ++fn)
                    acc[fm][fn] = __builtin_amdgcn_mfma_f32_16x16x32_bf16(
                        af[fm], bfr[fn], acc[fm][fn], 0, 0, 0);
        }
        __builtin_amdgcn_s_setprio(0);
        __syncthreads();                         // LDS reads of tile t done
        if (t < 3) {
            if (A_FP32) writeA_f32();            // compiler waits fa deps
            else        stageA_b16(t + 1);
            stageB(t + 1);
            __syncthreads();                     // tile t+1 ready
        }
    }

    // Epilogue
    float bv[4];
    #pragma unroll
    for (int fn = 0; fn < 4; ++fn) bv[fn] = biz[bn + wn + fn * 16 + lr];

    #pragma unroll
    for (int fm = 0; fm < 4; ++fm)
        #pragma unroll
        for (int fn = 0; fn < 4; ++fn)
            #pragma unroll
            for (int rr = 0; rr < 4; ++rr) {
                const int row = bm + wm + fm * 16 + lhi * 4 + rr;
                const int col = bn + wn + fn * 16 + lr;
                const float val = acc[fm][fn][rr] + bv[fn];
                if (A_FP32)   // QKV -> bf16 out
                    ((unsigned short*)Cz)[(size_t)row * 512 + col] = f2bf(val);
                else          // out-proj -> fp32 out
                    ((float*)Cz)[(size_t)row * 512 + col] = val;
            }
}

// ---------------------------------------------------------------------------
// MFMA banded-causal local attention (round-3 validated, unchanged).
// ---------------------------------------------------------------------------
__global__ __launch_bounds__(256)
void attn_mfma(const unsigned short* __restrict__ qb,
               const unsigned short* __restrict__ kb,
               const unsigned short* __restrict__ vb,
               unsigned short* __restrict__ ob)
{
    __shared__ unsigned short Ksh[192 * 64];
    __shared__ unsigned short Vsh[4 * 192 * 16];
    __shared__ unsigned short Psh[4 * 16 * 200];

    const int flat = blockIdx.x + 32 * (blockIdx.y + 8 * blockIdx.z);
    const int lg   = (flat & 7) * 128 + (flat >> 3);
    const int tile = lg & 31;
    const int h    = (lg >> 5) & 7;
    const int b    = lg >> 8;

    const int i0 = tile * 64;
    const int j0 = i0 - 128;
    const int tid = threadIdx.x;
    const int w   = tid >> 6;
    const int l   = tid & 63;
    const int lr  = l & 15;
    const int lhi = l >> 4;
    const float scale = 0.0220970869120796f;

    const size_t hbase = ((size_t)b * K_) * 512 + (size_t)h * 64;
    const unsigned short* kh = kb + hbase;
    const unsigned short* vh = vb + hbase;
    const unsigned short* qh = qb + hbase;
    unsigned short* oh = ob + hbase;

    #pragma unroll
    for (int it = 0; it < 6; ++it) {
        const int cg  = it * 4 + w;
        const int cid = cg * 64 + l;
        const int r = cid >> 3, c = cid & 7;
        const int cs = c ^ (r & 7);
        int j = j0 + r; if (j < 0) j = 0;
        gload_lds16(kh + (size_t)j * 512 + cs * 8, &Ksh[cg * 64 * 8]);
    }
    #pragma unroll
    for (int it = 0; it < 6; ++it) {
        const int cg  = it * 4 + w;
        const int cid = cg * 64 + l;
        const int blk = cid / 384;
        const int rem = cid - blk * 384;
        const int prow = rem >> 1, hf = rem & 1;
        const int a = prow >> 2, bb = prow & 3;
        const int k = (a < 24) ? (8 * a + bb) : (8 * (a - 24) + 4 + bb);
        int j = j0 + k; if (j < 0) j = 0;
        gload_lds16(vh + (size_t)j * 512 + blk * 16 + hf * 8, &Vsh[cg * 64 * 8]);
    }

    bf16x8 qa[2];
    {
        const unsigned short* qrow = qh + (size_t)(i0 + 16 * w + lr) * 512;
        qa[0] = *(const bf16x8*)(qrow + lhi * 8);
        qa[1] = *(const bf16x8*)(qrow + 32 + lhi * 8);
    }
    __syncthreads();

    const int jcbase = w & ~1;
    f32x4 sacc[10];
    #pragma unroll
    for (int jc = 0; jc < 10; ++jc) sacc[jc] = (f32x4){0.f, 0.f, 0.f, 0.f};

    __builtin_amdgcn_s_setprio(1);
    #pragma unroll
    for (int kk = 0; kk < 2; ++kk) {
        const int ch = (kk * 4 + lhi) ^ (lr & 7);
        #pragma unroll
        for (int jc = 0; jc < 10; ++jc) {
            const int row = (jcbase + jc) * 16 + lr;
            bf16x8 kf = *(const bf16x8*)&Ksh[row * 64 + ch * 8];
            sacc[jc] = __builtin_amdgcn_mfma_f32_16x16x32_bf16(
                qa[kk], kf, sacc[jc], 0, 0, 0);
        }
    }
    __builtin_amdgcn_s_setprio(0);

    unsigned short* myP = &Psh[w * 3200];
    const int lo0 = 128 - i0;
    float lsum[4] = {0.f, 0.f, 0.f, 0.f};
    #pragma unroll
    for (int jc = 0; jc < 10; ++jc) {
        const int jcol = (jcbase + jc) * 16 + lr;
        #pragma unroll
        for (int rr = 0; rr < 4; ++rr) {
            const int iloc = 16 * w + 4 * lhi + rr;
            const bool ok = (jcol >= iloc) && (jcol <= iloc + ATTN_) && (jcol >= lo0);
            const float p = ok ? __expf(fminf(sacc[jc][rr] * scale, 80.f)) : 0.f;
            lsum[rr] += p;
            myP[(4 * lhi + rr) * 200 + jcol] = f2bf(p);
        }
    }
    #pragma unroll
    for (int rr = 0; rr < 4; ++rr) {
        float s = lsum[rr];
        s += __shfl_xor(s, 1, 16);
        s += __shfl_xor(s, 2, 16);
        s += __shfl_xor(s, 4, 16);
        s += __shfl_xor(s, 8, 16);
        lsum[rr] = s;
    }

    const int kcbase = w >> 1;
    f32x4 oacc[4];
    #pragma unroll
    for (int fn = 0; fn < 4; ++fn) oacc[fn] = (f32x4){0.f, 0.f, 0.f, 0.f};
    const unsigned vbase = lds_addr(&Vsh[0]) + (unsigned)(l * 8);

    for (int kc5 = 0; kc5 < 5; ++kc5) {
        const int kc = kcbase + kc5;
        bf16x8 pa = *(const bf16x8*)&myP[lr * 200 + kc * 32 + lhi * 8];
        u32x2 vlo[4], vhi[4];
        #pragma unroll
        for (int fn = 0; fn < 4; ++fn) {
            const unsigned addr = vbase + (unsigned)((fn * 3072 + kc * 256) * 2);
            asm volatile("ds_read_b64_tr_b16 %0, %1" : "=v"(vlo[fn]) : "v"(addr));
            asm volatile("ds_read_b64_tr_b16 %0, %1 offset:3072"
                         : "=v"(vhi[fn]) : "v"(addr));
        }
        asm volatile("s_waitcnt lgkmcnt(0)" ::: "memory");
        __builtin_amdgcn_sched_barrier(0);
        __builtin_amdgcn_s_setprio(1);
        #pragma unroll
        for (int fn = 0; fn < 4; ++fn) {
            union { u32x2 h[2]; bf16x8 v; } u;
            u.h[0] = vlo[fn]; u.h[1] = vhi[fn];
            oacc[fn] = __builtin_amdgcn_mfma_f32_16x16x32_bf16(
                pa, u.v, oacc[fn], 0, 0, 0);
        }
        __builtin_amdgcn_s_setprio(0);
    }

    float inv[4];
    #pragma unroll
    for (int rr = 0; rr < 4; ++rr) inv[rr] = 1.f / lsum[rr];
    #pragma unroll
    for (int fn = 0; fn < 4; ++fn)
        #pragma unroll
        for (int rr = 0; rr < 4; ++rr) {
            const int row = i0 + 16 * w + 4 * lhi + rr;
            oh[(size_t)row * 512 + fn * 16 + lr] = f2bf(oacc[fn][rr] * inv[rr]);
        }
}

// ---------------------------------------------------------------------------
extern "C" void kernel_launch(void* const* d_in, const int* in_sizes, int n_in,
                              void* d_out, int out_size, void* d_ws, size_t ws_size,
                              hipStream_t stream)
{
    const float* query = (const float*)d_in[0];
    const float* key   = (const float*)d_in[1];
    const float* value = (const float*)d_in[2];
    const float* W_q   = (const float*)d_in[3];
    const float* b_q   = (const float*)d_in[4];
    const float* W_k   = (const float*)d_in[5];
    const float* b_k   = (const float*)d_in[6];
    const float* W_v   = (const float*)d_in[7];
    const float* b_v   = (const float*)d_in[8];
    const float* W_o   = (const float*)d_in[9];
    const float* b_o   = (const float*)d_in[10];
    float* out = (float*)d_out;

    const size_t NX = (size_t)M_ * 512;
    const size_t NW = 512 * 512;
    unsigned short* wqb = (unsigned short*)d_ws;
    unsigned short* wkb = wqb + NW;
    unsigned short* wvb = wkb + NW;
    unsigned short* wob = wvb + NW;
    unsigned short* qp  = wob + NW;
    unsigned short* kp  = qp + NX;
    unsigned short* vp  = kp + NX;
    unsigned short* ap  = vp + NX;

    const int NW8 = (int)(NW / 8);

    CvtA a;
    a.c[0] = { W_q, wqb, NW8 };
    a.c[1] = { W_k, wkb, NW8 };
    a.c[2] = { W_v, wvb, NW8 };
    a.c[3] = { W_o, wob, NW8 };
    cvt_multi<<<dim3(32, 4), 256, 0, stream>>>(a);

    GArgs qa;
    qa.A[0] = query; qa.A[1] = key; qa.A[2] = value;
    qa.Wt[0] = wqb;  qa.Wt[1] = wkb; qa.Wt[2] = wvb;
    qa.bias[0] = b_q; qa.bias[1] = b_k; qa.bias[2] = b_v;
    qa.C[0] = qp; qa.C[1] = kp; qa.C[2] = vp;
    gemm128k<true><<<768, 256, 0, stream>>>(qa);   // 192 m-groups x 4 nt

    attn_mfma<<<dim3(32, 8, 4), 256, 0, stream>>>(qp, kp, vp, ap);

    GArgs oa;
    oa.A[0] = ap; oa.A[1] = ap; oa.A[2] = ap;
    oa.Wt[0] = wob; oa.Wt[1] = wob; oa.Wt[2] = wob;
    oa.bias[0] = b_o; oa.bias[1] = b_o; oa.bias[2] = b_o;
    oa.C[0] = out; oa.C[1] = out; oa.C[2] = out;
    gemm128k<false><<<256, 256, 0, stream>>>(oa);  // 64 m-groups x 4 nt
}

// Round 14
// 56.287 us; speedup vs baseline: 1.0910x; 1.0910x over previous
//
#include <hip/hip_runtime.h>
#include <hip/hip_bf16.h>
#include <stdint.h>

#define B_ 4
#define K_ 2048
#define D_ 512
#define H_ 8
#define ATTN_ 128
#define M_ (B_ * K_)   // 8192

typedef __attribute__((ext_vector_type(4))) float f32x4;
typedef __attribute__((ext_vector_type(8))) short bf16x8;
typedef __attribute__((ext_vector_type(8))) unsigned short u16x8;
typedef __attribute__((ext_vector_type(2))) unsigned int u32x2;

__device__ __forceinline__ unsigned short f2bf(float f) {
    union { float f; unsigned int i; } x; x.f = f;
    unsigned int r = x.i + 0x7fffu + ((x.i >> 16) & 1u);   // RNE
    return (unsigned short)(r >> 16);
}
__device__ __forceinline__ float bf2f(unsigned short u) {
    union { unsigned int i; float f; } x; x.i = ((unsigned int)u) << 16; return x.f;
}
__device__ __forceinline__ void gload_lds16(const unsigned short* g, unsigned short* l) {
    __builtin_amdgcn_global_load_lds(
        (const __attribute__((address_space(1))) void*)g,
        (__attribute__((address_space(3))) void*)l, 16, 0, 0);
}
__device__ __forceinline__ unsigned lds_addr(const void* p) {
    return (unsigned)(unsigned long long)
        (const __attribute__((address_space(3))) void*)p;
}

// ---------------------------------------------------------------------------
// fp32 -> bf16 conversion: weights only (4 tensors)
// ---------------------------------------------------------------------------
struct Cvt { const float* s; unsigned short* d; int n8; };
struct CvtA { Cvt c[4]; };

__global__ __launch_bounds__(256)
void cvt_multi(CvtA a) {
    const Cvt c = a.c[blockIdx.y];
    const float4* s4 = (const float4*)c.s;
    u16x8* d8 = (u16x8*)c.d;
    for (int g = blockIdx.x * 256 + threadIdx.x; g < c.n8; g += gridDim.x * 256) {
        float4 f0 = s4[2 * g], f1 = s4[2 * g + 1];
        u16x8 o;
        o[0] = f2bf(f0.x); o[1] = f2bf(f0.y); o[2] = f2bf(f0.z); o[3] = f2bf(f0.w);
        o[4] = f2bf(f1.x); o[5] = f2bf(f1.y); o[6] = f2bf(f1.z); o[7] = f2bf(f1.w);
        d8[g] = o;
    }
}

// ---------------------------------------------------------------------------
// QKV GEMM — the r4 x r12 union (m97 mechanism):
//   128x128 tile, BK=64, 256 thr (4 waves 2x2), 3 blocks/CU (48 KB LDS)
//   AND double-buffered B so staging issues BEFORE compute.
// Per step t: issue loadA(t+1)->reg and stageB(t+1)->Bs[buf^1] FIRST (full
// ~1300-cyc compute phase of latency cover), then 64 MFMA on (As, Bs[buf]),
// then barrier1 (vmcnt drain retires long-landed loads: ~free; also the
// As read-drain), writeA cvt+ds_write (tile t+1's A), barrier2 (lgkm: ~free).
// r12's single buffer forced stageB AFTER compute -> fresh ~900-cyc drain
// every step; that was the residual 39us. A stays single-buffered (written
// only after the read-drain barrier -> race-free).
// Fragment layout / XOR swizzle / grid map: r12-validated, unchanged.
// ---------------------------------------------------------------------------
struct GArgs {
    const void* A[3];
    const unsigned short* Wt[3];
    const float* bias[3];
    void* C[3];
};

__global__ __launch_bounds__(256, 3)
void gemm_qkv128(GArgs args)
{
    __shared__ unsigned short As[128 * 64];      // 16 KB (single)
    __shared__ unsigned short Bs[2][128 * 64];   // 32 KB (double)

    const int id = blockIdx.x;
    const int lg = (id & 7) * (gridDim.x >> 3) + (id >> 3);  // XCD-contiguous
    const int g  = lg >> 2;                      // m-group (shares A-tile)
    const int nt = lg & 3;
    const int z  = g >> 6;
    const int mt = g & 63;
    const int bm = mt * 128;
    const int bn = nt * 128;

    const float* Az = (const float*)args.A[z];
    const unsigned short* Wz = args.Wt[z];
    const float* biz = args.bias[z];
    unsigned short* Cz = (unsigned short*)args.C[z];

    const int tid = threadIdx.x;
    const int w   = tid >> 6;                    // wave 0..3
    const int l   = tid & 63;
    const int lr  = l & 15;
    const int lhi = l >> 4;
    const int wm  = (w >> 1) * 64;               // 2x2 wave grid
    const int wn  = (w & 1) * 64;

    f32x4 acc[4][4];
    #pragma unroll
    for (int m = 0; m < 4; ++m)
        #pragma unroll
        for (int n = 0; n < 4; ++n) acc[m][n] = (f32x4){0.f, 0.f, 0.f, 0.f};

    float4 fa[4][2];   // in-flight fp32 A tile (32 VGPR)

    auto loadA_f32 = [&](int t) {                // 8 float4 / thread
        #pragma unroll
        for (int q = 0; q < 4; ++q) {
            const int cid = q * 256 + tid;       // 1024 chunks: 128 rows x 8
            const int r = cid >> 3;
            const int c = (cid & 7) ^ (r & 7);   // load-side XOR permutation
            const float* src = Az + (size_t)(bm + r) * D_ + t * 64 + c * 8;
            fa[q][0] = *(const float4*)src;
            fa[q][1] = *(const float4*)(src + 4);
        }
    };
    auto writeA_f32 = [&]() {                    // cvt + 4 ds_write_b128
        #pragma unroll
        for (int q = 0; q < 4; ++q) {
            const int cid = q * 256 + tid;
            u16x8 o;
            o[0] = f2bf(fa[q][0].x); o[1] = f2bf(fa[q][0].y);
            o[2] = f2bf(fa[q][0].z); o[3] = f2bf(fa[q][0].w);
            o[4] = f2bf(fa[q][1].x); o[5] = f2bf(fa[q][1].y);
            o[6] = f2bf(fa[q][1].z); o[7] = f2bf(fa[q][1].w);
            *(u16x8*)&As[cid * 8] = o;           // linear dest: conflict-free
        }
    };
    auto stageB = [&](int buf, int t) {          // 4 gload_lds / wave
        #pragma unroll
        for (int it = 0; it < 4; ++it) {
            const int cg  = it * 4 + w;
            const int cid = cg * 64 + l;
            const int r = cid >> 3;
            const int c = (cid & 7) ^ (r & 7);
            gload_lds16(Wz + (size_t)(bn + r) * D_ + t * 64 + c * 8,
                        &Bs[buf][cg * 512]);
        }
    };

    // Prologue: tile 0 fully staged, drained.
    loadA_f32(0);
    writeA_f32();                                // waits fa deps (one-time cost)
    stageB(0, 0);
    __syncthreads();

    for (int t = 0; t < 8; ++t) {                // K = 512 = 8 x 64
        // Issue next tile's loads BEFORE compute: full phase of latency cover.
        if (t < 7) {
            loadA_f32(t + 1);                    // global->reg (flies)
            stageB((t + 1) & 1, t + 1);          // gload_lds -> other buffer
        }
        __builtin_amdgcn_s_setprio(1);
        #pragma unroll
        for (int kk = 0; kk < 2; ++kk) {
            bf16x8 af[4], bfr[4];
            #pragma unroll
            for (int fm = 0; fm < 4; ++fm) {
                const int row = wm + fm * 16 + lr;
                const int sl  = (kk * 4 + lhi) ^ (row & 7);
                af[fm] = *(const bf16x8*)&As[row * 64 + sl * 8];
            }
            #pragma unroll
            for (int fn = 0; fn < 4; ++fn) {
                const int row = wn + fn * 16 + lr;
                const int sl  = (kk * 4 + lhi) ^ (row & 7);
                bfr[fn] = *(const bf16x8*)&Bs[t & 1][row * 64 + sl * 8];
            }
            #pragma unroll
            for (int fm = 0; fm < 4; ++fm)
                #pragma unroll
                for (int fn = 0; fn < 4; ++fn)
                    acc[fm][fn] = __builtin_amdgcn_mfma_f32_16x16x32_bf16(
                        af[fm], bfr[fn], acc[fm][fn], 0, 0, 0);
        }
        __builtin_amdgcn_s_setprio(0);
        if (t < 7) {
            __syncthreads();     // As read-drain + vmcnt (loads long landed)
            writeA_f32();        // tile t+1's A -> As (cvt + ds_write)
            __syncthreads();     // lgkm drain: As visible for next step
        }
    }

    // Epilogue: bf16 out
    float bv[4];
    #pragma unroll
    for (int fn = 0; fn < 4; ++fn) bv[fn] = biz[bn + wn + fn * 16 + lr];

    #pragma unroll
    for (int fm = 0; fm < 4; ++fm)
        #pragma unroll
        for (int fn = 0; fn < 4; ++fn)
            #pragma unroll
            for (int rr = 0; rr < 4; ++rr) {
                const int row = bm + wm + fm * 16 + lhi * 4 + rr;
                const int col = bn + wn + fn * 16 + lr;
                Cz[(size_t)row * 512 + col] = f2bf(acc[fm][fn][rr] + bv[fn]);
            }
}

// ---------------------------------------------------------------------------
// Out-projection GEMM — m97-verbatim: A+B both gload_lds, both double-
// buffered (64 KB), stage(t+1) issued BEFORE compute, ONE barrier per step.
// ---------------------------------------------------------------------------
__global__ __launch_bounds__(256, 2)
void gemm_o128(const unsigned short* __restrict__ A,
               const unsigned short* __restrict__ W,
               const float* __restrict__ bias,
               float* __restrict__ C)
{
    __shared__ unsigned short As[2][128 * 64];   // 32 KB
    __shared__ unsigned short Bs[2][128 * 64];   // 32 KB

    const int id = blockIdx.x;
    const int lg = (id & 7) * (gridDim.x >> 3) + (id >> 3);
    const int mt = lg >> 2;
    const int nt = lg & 3;
    const int bm = mt * 128;
    const int bn = nt * 128;

    const int tid = threadIdx.x;
    const int w   = tid >> 6;
    const int l   = tid & 63;
    const int lr  = l & 15;
    const int lhi = l >> 4;
    const int wm  = (w >> 1) * 64;
    const int wn  = (w & 1) * 64;

    f32x4 acc[4][4];
    #pragma unroll
    for (int m = 0; m < 4; ++m)
        #pragma unroll
        for (int n = 0; n < 4; ++n) acc[m][n] = (f32x4){0.f, 0.f, 0.f, 0.f};

    auto stage = [&](int buf, int t) {
        #pragma unroll
        for (int it = 0; it < 4; ++it) {
            const int cg  = it * 4 + w;
            const int cid = cg * 64 + l;
            const int r = cid >> 3;
            const int c = (cid & 7) ^ (r & 7);
            gload_lds16(A + (size_t)(bm + r) * D_ + t * 64 + c * 8,
                        &As[buf][cg * 512]);
        }
        #pragma unroll
        for (int it = 0; it < 4; ++it) {
            const int cg  = it * 4 + w;
            const int cid = cg * 64 + l;
            const int r = cid >> 3;
            const int c = (cid & 7) ^ (r & 7);
            gload_lds16(W + (size_t)(bn + r) * D_ + t * 64 + c * 8,
                        &Bs[buf][cg * 512]);
        }
    };

    stage(0, 0);
    __syncthreads();

    int buf = 0;
    for (int t = 0; t < 8; ++t) {
        if (t < 7) stage(buf ^ 1, t + 1);        // issue BEFORE compute
        __builtin_amdgcn_s_setprio(1);
        #pragma unroll
        for (int kk = 0; kk < 2; ++kk) {
            bf16x8 af[4], bfr[4];
            #pragma unroll
            for (int fm = 0; fm < 4; ++fm) {
                const int row = wm + fm * 16 + lr;
                const int sl  = (kk * 4 + lhi) ^ (row & 7);
                af[fm] = *(const bf16x8*)&As[buf][row * 64 + sl * 8];
            }
            #pragma unroll
            for (int fn = 0; fn < 4; ++fn) {
                const int row = wn + fn * 16 + lr;
                const int sl  = (kk * 4 + lhi) ^ (row & 7);
                bfr[fn] = *(const bf16x8*)&Bs[buf][row * 64 + sl * 8];
            }
            #pragma unroll
            for (int fm = 0; fm < 4; ++fm)
                #pragma unroll
                for (int fn = 0; fn < 4; ++fn)
                    acc[fm][fn] = __builtin_amdgcn_mfma_f32_16x16x32_bf16(
                        af[fm], bfr[fn], acc[fm][fn], 0, 0, 0);
        }
        __builtin_amdgcn_s_setprio(0);
        __syncthreads();                         // loads had full compute to land
        buf ^= 1;
    }

    float bv[4];
    #pragma unroll
    for (int fn = 0; fn < 4; ++fn) bv[fn] = bias[bn + wn + fn * 16 + lr];

    #pragma unroll
    for (int fm = 0; fm < 4; ++fm)
        #pragma unroll
        for (int fn = 0; fn < 4; ++fn)
            #pragma unroll
            for (int rr = 0; rr < 4; ++rr) {
                const int row = bm + wm + fm * 16 + lhi * 4 + rr;
                const int col = bn + wn + fn * 16 + lr;
                C[(size_t)row * 512 + col] = acc[fm][fn][rr] + bv[fn];
            }
}

// ---------------------------------------------------------------------------
// MFMA banded-causal local attention (round-3 validated, unchanged).
// ---------------------------------------------------------------------------
__global__ __launch_bounds__(256)
void attn_mfma(const unsigned short* __restrict__ qb,
               const unsigned short* __restrict__ kb,
               const unsigned short* __restrict__ vb,
               unsigned short* __restrict__ ob)
{
    __shared__ unsigned short Ksh[192 * 64];
    __shared__ unsigned short Vsh[4 * 192 * 16];
    __shared__ unsigned short Psh[4 * 16 * 200];

    const int flat = blockIdx.x + 32 * (blockIdx.y + 8 * blockIdx.z);
    const int lg   = (flat & 7) * 128 + (flat >> 3);
    const int tile = lg & 31;
    const int h    = (lg >> 5) & 7;
    const int b    = lg >> 8;

    const int i0 = tile * 64;
    const int j0 = i0 - 128;
    const int tid = threadIdx.x;
    const int w   = tid >> 6;
    const int l   = tid & 63;
    const int lr  = l & 15;
    const int lhi = l >> 4;
    const float scale = 0.0220970869120796f;

    const size_t hbase = ((size_t)b * K_) * 512 + (size_t)h * 64;
    const unsigned short* kh = kb + hbase;
    const unsigned short* vh = vb + hbase;
    const unsigned short* qh = qb + hbase;
    unsigned short* oh = ob + hbase;

    #pragma unroll
    for (int it = 0; it < 6; ++it) {
        const int cg  = it * 4 + w;
        const int cid = cg * 64 + l;
        const int r = cid >> 3, c = cid & 7;
        const int cs = c ^ (r & 7);
        int j = j0 + r; if (j < 0) j = 0;
        gload_lds16(kh + (size_t)j * 512 + cs * 8, &Ksh[cg * 64 * 8]);
    }
    #pragma unroll
    for (int it = 0; it < 6; ++it) {
        const int cg  = it * 4 + w;
        const int cid = cg * 64 + l;
        const int blk = cid / 384;
        const int rem = cid - blk * 384;
        const int prow = rem >> 1, hf = rem & 1;
        const int a = prow >> 2, bb = prow & 3;
        const int k = (a < 24) ? (8 * a + bb) : (8 * (a - 24) + 4 + bb);
        int j = j0 + k; if (j < 0) j = 0;
        gload_lds16(vh + (size_t)j * 512 + blk * 16 + hf * 8, &Vsh[cg * 64 * 8]);
    }

    bf16x8 qa[2];
    {
        const unsigned short* qrow = qh + (size_t)(i0 + 16 * w + lr) * 512;
        qa[0] = *(const bf16x8*)(qrow + lhi * 8);
        qa[1] = *(const bf16x8*)(qrow + 32 + lhi * 8);
    }
    __syncthreads();

    const int jcbase = w & ~1;
    f32x4 sacc[10];
    #pragma unroll
    for (int jc = 0; jc < 10; ++jc) sacc[jc] = (f32x4){0.f, 0.f, 0.f, 0.f};

    __builtin_amdgcn_s_setprio(1);
    #pragma unroll
    for (int kk = 0; kk < 2; ++kk) {
        const int ch = (kk * 4 + lhi) ^ (lr & 7);
        #pragma unroll
        for (int jc = 0; jc < 10; ++jc) {
            const int row = (jcbase + jc) * 16 + lr;
            bf16x8 kf = *(const bf16x8*)&Ksh[row * 64 + ch * 8];
            sacc[jc] = __builtin_amdgcn_mfma_f32_16x16x32_bf16(
                qa[kk], kf, sacc[jc], 0, 0, 0);
        }
    }
    __builtin_amdgcn_s_setprio(0);

    unsigned short* myP = &Psh[w * 3200];
    const int lo0 = 128 - i0;
    float lsum[4] = {0.f, 0.f, 0.f, 0.f};
    #pragma unroll
    for (int jc = 0; jc < 10; ++jc) {
        const int jcol = (jcbase + jc) * 16 + lr;
        #pragma unroll
        for (int rr = 0; rr < 4; ++rr) {
            const int iloc = 16 * w + 4 * lhi + rr;
            const bool ok = (jcol >= iloc) && (jcol <= iloc + ATTN_) && (jcol >= lo0);
            const float p = ok ? __expf(fminf(sacc[jc][rr] * scale, 80.f)) : 0.f;
            lsum[rr] += p;
            myP[(4 * lhi + rr) * 200 + jcol] = f2bf(p);
        }
    }
    #pragma unroll
    for (int rr = 0; rr < 4; ++rr) {
        float s = lsum[rr];
        s += __shfl_xor(s, 1, 16);
        s += __shfl_xor(s, 2, 16);
        s += __shfl_xor(s, 4, 16);
        s += __shfl_xor(s, 8, 16);
        lsum[rr] = s;
    }

    const int kcbase = w >> 1;
    f32x4 oacc[4];
    #pragma unroll
    for (int fn = 0; fn < 4; ++fn) oacc[fn] = (f32x4){0.f, 0.f, 0.f, 0.f};
    const unsigned vbase = lds_addr(&Vsh[0]) + (unsigned)(l * 8);

    for (int kc5 = 0; kc5 < 5; ++kc5) {
        const int kc = kcbase + kc5;
        bf16x8 pa = *(const bf16x8*)&myP[lr * 200 + kc * 32 + lhi * 8];
        u32x2 vlo[4], vhi[4];
        #pragma unroll
        for (int fn = 0; fn < 4; ++fn) {
            const unsigned addr = vbase + (unsigned)((fn * 3072 + kc * 256) * 2);
            asm volatile("ds_read_b64_tr_b16 %0, %1" : "=v"(vlo[fn]) : "v"(addr));
            asm volatile("ds_read_b64_tr_b16 %0, %1 offset:3072"
                         : "=v"(vhi[fn]) : "v"(addr));
        }
        asm volatile("s_waitcnt lgkmcnt(0)" ::: "memory");
        __builtin_amdgcn_sched_barrier(0);
        __builtin_amdgcn_s_setprio(1);
        #pragma unroll
        for (int fn = 0; fn < 4; ++fn) {
            union { u32x2 h[2]; bf16x8 v; } u;
            u.h[0] = vlo[fn]; u.h[1] = vhi[fn];
            oacc[fn] = __builtin_amdgcn_mfma_f32_16x16x32_bf16(
                pa, u.v, oacc[fn], 0, 0, 0);
        }
        __builtin_amdgcn_s_setprio(0);
    }

    float inv[4];
    #pragma unroll
    for (int rr = 0; rr < 4; ++rr) inv[rr] = 1.f / lsum[rr];
    #pragma unroll
    for (int fn = 0; fn < 4; ++fn)
        #pragma unroll
        for (int rr = 0; rr < 4; ++rr) {
            const int row = i0 + 16 * w + 4 * lhi + rr;
            oh[(size_t)row * 512 + fn * 16 + lr] = f2bf(oacc[fn][rr] * inv[rr]);
        }
}

// ---------------------------------------------------------------------------
extern "C" void kernel_launch(void* const* d_in, const int* in_sizes, int n_in,
                              void* d_out, int out_size, void* d_ws, size_t ws_size,
                              hipStream_t stream)
{
    const float* query = (const float*)d_in[0];
    const float* key   = (const float*)d_in[1];
    const float* value = (const float*)d_in[2];
    const float* W_q   = (const float*)d_in[3];
    const float* b_q   = (const float*)d_in[4];
    const float* W_k   = (const float*)d_in[5];
    const float* b_k   = (const float*)d_in[6];
    const float* W_v   = (const float*)d_in[7];
    const float* b_v   = (const float*)d_in[8];
    const float* W_o   = (const float*)d_in[9];
    const float* b_o   = (const float*)d_in[10];
    float* out = (float*)d_out;

    const size_t NX = (size_t)M_ * 512;
    const size_t NW = 512 * 512;
    unsigned short* wqb = (unsigned short*)d_ws;
    unsigned short* wkb = wqb + NW;
    unsigned short* wvb = wkb + NW;
    unsigned short* wob = wvb + NW;
    unsigned short* qp  = wob + NW;
    unsigned short* kp  = qp + NX;
    unsigned short* vp  = kp + NX;
    unsigned short* ap  = vp + NX;

    const int NW8 = (int)(NW / 8);

    CvtA a;
    a.c[0] = { W_q, wqb, NW8 };
    a.c[1] = { W_k, wkb, NW8 };
    a.c[2] = { W_v, wvb, NW8 };
    a.c[3] = { W_o, wob, NW8 };
    cvt_multi<<<dim3(32, 4), 256, 0, stream>>>(a);

    GArgs qa;
    qa.A[0] = query; qa.A[1] = key; qa.A[2] = value;
    qa.Wt[0] = wqb;  qa.Wt[1] = wkb; qa.Wt[2] = wvb;
    qa.bias[0] = b_q; qa.bias[1] = b_k; qa.bias[2] = b_v;
    qa.C[0] = qp; qa.C[1] = kp; qa.C[2] = vp;
    gemm_qkv128<<<768, 256, 0, stream>>>(qa);    // 192 m-groups x 4 nt

    attn_mfma<<<dim3(32, 8, 4), 256, 0, stream>>>(qp, kp, vp, ap);

    gemm_o128<<<256, 256, 0, stream>>>(ap, wob, b_o, out);  // 64 mt x 4 nt
}